// Round 12
// baseline (5130.445 us; speedup 1.0000x reference)
//
#include <hip/hip_runtime.h>

typedef __bf16 bf16;
typedef __attribute__((ext_vector_type(8))) __bf16 bf16x8;
typedef __attribute__((ext_vector_type(4))) __bf16 bf16x4;
typedef __attribute__((ext_vector_type(4))) float f32x4;

#define MFMA16(a,b,c) __builtin_amdgcn_mfma_f32_16x16x32_bf16((a),(b),(c),0,0,0)
#define RMS_EPS 1.1920929e-07f

__device__ __forceinline__ void gload16(const void* g, void* l) {
    __builtin_amdgcn_global_load_lds((const __attribute__((address_space(1))) void*)g,
                                     (__attribute__((address_space(3))) void*)l, 16, 0, 0);
}

// bijective XCD-chunked block swizzle (m204)
__device__ __forceinline__ int xcd_swizzle(int orig, int nwg) {
    int q = nwg >> 3, r = nwg & 7;
    int xcd = orig & 7, loc = orig >> 3;
    int base = (xcd < r) ? xcd * (q + 1) : r * (q + 1) + (xcd - r) * q;
    return base + loc;
}

// ---------------- elementwise / small kernels ----------------

__global__ __launch_bounds__(256) void cvt_kernel(const float* __restrict__ in,
                                                  bf16* __restrict__ out, int n4) {
    int stride = gridDim.x * 256;
    for (int i = blockIdx.x * 256 + threadIdx.x; i < n4; i += stride) {
        float4 v = ((const float4*)in)[i];
        bf16x4 o;
        o[0] = (bf16)v.x; o[1] = (bf16)v.y; o[2] = (bf16)v.z; o[3] = (bf16)v.w;
        ((bf16x4*)out)[i] = o;
    }
}

// WG[s][c] = norm_w[c] * scale_gamma[s][c], for norm1 (which=0) and norm2 (which=1)
__global__ __launch_bounds__(256) void wg_kernel(const float* __restrict__ norm1_w,
                                                 const float* __restrict__ norm2_w,
                                                 const float* __restrict__ scale_gamma,
                                                 float* __restrict__ WG1,
                                                 float* __restrict__ WG2) {
    int b = blockIdx.x;            // 8 blocks: s = b>>1, which = b&1
    int s = b >> 1, which = b & 1;
    int c = threadIdx.x * 4;
    float4 g = *(const float4*)(scale_gamma + s * 1024 + c);
    const float* w = which ? norm2_w : norm1_w;
    float* dst = which ? WG2 : WG1;
    float4 wv = *(const float4*)(w + c);
    float4 o = {wv.x * g.x, wv.y * g.y, wv.z * g.z, wv.w * g.w};
    *(float4*)(dst + s * 1024 + c) = o;
}

// embed + row-sumsq (slice 0 = total, slices 1..7 = 0)
__global__ __launch_bounds__(256) void embed_kernel(const int* __restrict__ tok,
                                                    const float* __restrict__ ew,
                                                    float* __restrict__ X,
                                                    float* __restrict__ SQ0) {
    int m = blockIdx.x, t = threadIdx.x;
    int tk = tok[m];
    float4 v = ((const float4*)(ew + (size_t)tk * 1024))[t];
    ((float4*)(X + (size_t)m * 1024))[t] = v;
    float ss = v.x * v.x + v.y * v.y + v.z * v.z + v.w * v.w;
#pragma unroll
    for (int off = 1; off < 64; off <<= 1) ss += __shfl_xor(ss, off);
    __shared__ float red[4];
    if ((t & 63) == 0) red[t >> 6] = ss;
    __syncthreads();
    float tot = red[0] + red[1] + red[2] + red[3];
    if (t < 8) SQ0[t * 2048 + m] = (t == 0) ? tot : 0.f;
}

// final norm (unchanged standalone)
__global__ __launch_bounds__(256) void rmsnorm_kernel(const float* __restrict__ X,
                                                      const float* __restrict__ w,
                                                      bf16* __restrict__ H) {
    int m = blockIdx.x, t = threadIdx.x;
    float4 xv = ((const float4*)(X + (size_t)m * 1024))[t];
    float ss = xv.x * xv.x + xv.y * xv.y + xv.z * xv.z + xv.w * xv.w;
#pragma unroll
    for (int off = 1; off < 64; off <<= 1) ss += __shfl_xor(ss, off);
    __shared__ float red[4];
    if ((t & 63) == 0) red[t >> 6] = ss;
    __syncthreads();
    float tot = red[0] + red[1] + red[2] + red[3];
    float sc = rsqrtf(tot * (1.0f / 1024.0f) + RMS_EPS);
    float4 wv = ((const float4*)w)[t];
    bf16x4 o;
    o[0] = (bf16)(xv.x * sc * wv.x); o[1] = (bf16)(xv.y * sc * wv.y);
    o[2] = (bf16)(xv.z * sc * wv.z); o[3] = (bf16)(xv.w * sc * wv.w);
    ((bf16x4*)(H + (size_t)m * 1024))[t] = o;
}

// ---------------- norm-fused A-staging helper ----------------
// Stage As[cid*8..+8) = bf16( X[row0+r][kt+c8 .. +8] * srms[r] * WG[c] + BT[c] )
template <int NCH>
__device__ __forceinline__ void stage_a_norm(const float* __restrict__ Xs, int row0, int kt,
                                             const float* __restrict__ WG,
                                             const float* __restrict__ BT,
                                             const float* __restrict__ srms,
                                             bf16* __restrict__ As, int tid) {
#pragma unroll
    for (int i = 0; i < NCH; ++i) {
        int cid = i * 256 + tid;
        int r = cid >> 3, c8 = (cid & 7) * 8;
        const float* xp = Xs + (size_t)(row0 + r) * 1024 + kt + c8;
        float4 xa = *(const float4*)xp, xb = *(const float4*)(xp + 4);
        float4 wa = *(const float4*)(WG + kt + c8), wb = *(const float4*)(WG + kt + c8 + 4);
        float4 ba = *(const float4*)(BT + kt + c8), bb = *(const float4*)(BT + kt + c8 + 4);
        float sc = srms[r];
        bf16x8 hv;
        hv[0] = (bf16)(xa.x * sc * wa.x + ba.x);
        hv[1] = (bf16)(xa.y * sc * wa.y + ba.y);
        hv[2] = (bf16)(xa.z * sc * wa.z + ba.z);
        hv[3] = (bf16)(xa.w * sc * wa.w + ba.w);
        hv[4] = (bf16)(xb.x * sc * wb.x + bb.x);
        hv[5] = (bf16)(xb.y * sc * wb.y + bb.y);
        hv[6] = (bf16)(xb.z * sc * wb.z + bb.z);
        hv[7] = (bf16)(xb.w * sc * wb.w + bb.w);
        *(bf16x8*)(As + cid * 8) = hv;
    }
}

// ---------------- plain GEMM body (B^T), used by lm_head ----------------
template <int MT, int MODE, bool BNF>
__device__ __forceinline__ void gemm_body(const bf16* __restrict__ A,
                                          const bf16* __restrict__ B,
                                          int GN, int GM, int N, int K,
                                          bf16* __restrict__ Cb, float* __restrict__ Cf) {
    constexpr int BM = 32 * MT;
    __shared__ __align__(16) bf16 As[BM * 64];
    __shared__ __align__(16) bf16 Bs[128 * 64];
    const int wg = xcd_swizzle(blockIdx.x, GN * GM);
    int bn, bm;
    if (BNF) { bm = wg / GN; bn = wg - bm * GN; }
    else     { bn = wg / GM; bm = wg - bn * GM; }
    const int tid = threadIdx.x, lane = tid & 63, w = tid >> 6;
    const int wr = w >> 1, wc = w & 1, lr = lane & 15, lg = lane >> 4;
    const bf16* Ab = A + (size_t)bm * BM * K;
    const bf16* Bb = B + (size_t)bn * 128 * K;

    f32x4 acc[MT][4];
#pragma unroll
    for (int i = 0; i < MT; ++i)
#pragma unroll
        for (int j = 0; j < 4; ++j) acc[i][j] = (f32x4){0.f, 0.f, 0.f, 0.f};

    for (int kt = 0; kt < K; kt += 64) {
        __syncthreads();
#pragma unroll
        for (int i = 0; i < MT; ++i) {
            int cw = i * 256 + w * 64;
            int cid = cw + lane;
            gload16(Ab + (size_t)(cid >> 3) * K + kt + (cid & 7) * 8, As + cw * 8);
        }
#pragma unroll
        for (int i = 0; i < 4; ++i) {
            int cw = i * 256 + w * 64;
            int cid = cw + lane;
            gload16(Bb + (size_t)(cid >> 3) * K + kt + (cid & 7) * 8, Bs + cw * 8);
        }
        __syncthreads();
#pragma unroll
        for (int kk = 0; kk < 64; kk += 32) {
            bf16x8 af[MT], bfr[4];
#pragma unroll
            for (int mi = 0; mi < MT; ++mi)
                af[mi] = *(const bf16x8*)(As + (wr * (16 * MT) + mi * 16 + lr) * 64 + kk + lg * 8);
#pragma unroll
            for (int ni = 0; ni < 4; ++ni)
                bfr[ni] = *(const bf16x8*)(Bs + (wc * 64 + ni * 16 + lr) * 64 + kk + lg * 8);
#pragma unroll
            for (int mi = 0; mi < MT; ++mi)
#pragma unroll
                for (int ni = 0; ni < 4; ++ni)
                    acc[mi][ni] = MFMA16(af[mi], bfr[ni], acc[mi][ni]);
        }
    }

#pragma unroll
    for (int mi = 0; mi < MT; ++mi) {
#pragma unroll
        for (int ni = 0; ni < 4; ++ni) {
#pragma unroll
            for (int j = 0; j < 4; ++j) {
                int row = bm * BM + wr * (16 * MT) + mi * 16 + lg * 4 + j;
                int col = bn * 128 + wc * 64 + ni * 16 + lr;
                size_t idx = (size_t)row * N + col;
                if (MODE == 0) Cb[idx] = (bf16)acc[mi][ni][j];
                else Cf[idx] = acc[mi][ni][j];
            }
        }
    }
}

// lm_head: MT=4 + 128-reg cap (measured best: r8 vs r9 A/B)
__global__ __launch_bounds__(256, 4) void gemm_lmhead(const bf16* A, const bf16* B, int GN, int GM,
                                                      int N, int K, float* Cf) {
    gemm_body<4, 3, false>(A, B, GN, GM, N, K, nullptr, Cf);
}

// ---------------- QKV GEMM, norm-fused A, V-transpose epilogue ----------------
// BM=64 (MT=2), bm-fastest. A comes from f32 X + SUMSQ0 slices.
__global__ __launch_bounds__(256, 4) void gemm_qkv(const float* __restrict__ X,
                                                   const float* __restrict__ SQ0,
                                                   const float* __restrict__ WG,
                                                   const float* __restrict__ BT,
                                                   const bf16* __restrict__ B,
                                                   bf16* __restrict__ Cb,
                                                   bf16* __restrict__ VTp) {
    const int GN = 24, GM = 32, N = 3072, K = 1024;
    __shared__ __align__(16) bf16 As[64 * 64];
    __shared__ __align__(16) bf16 Bs[128 * 64];
    __shared__ float srms[64];
    const int wg = xcd_swizzle(blockIdx.x, GN * GM);
    const int bn = wg / GM, bm = wg - bn * GM;
    const int tid = threadIdx.x, lane = tid & 63, w = tid >> 6;
    const int wr = w >> 1, wc = w & 1, lr = lane & 15, lg = lane >> 4;
    const int row0 = bm * 64;
    const bf16* Bb = B + (size_t)bn * 128 * K;

    if (tid < 64) {
        float s = 0.f;
#pragma unroll
        for (int k = 0; k < 8; ++k) s += SQ0[k * 2048 + row0 + tid];
        srms[tid] = rsqrtf(s * (1.0f / 1024.0f) + RMS_EPS);
    }

    f32x4 acc[2][4];
#pragma unroll
    for (int i = 0; i < 2; ++i)
#pragma unroll
        for (int j = 0; j < 4; ++j) acc[i][j] = (f32x4){0.f, 0.f, 0.f, 0.f};

    for (int kt = 0; kt < K; kt += 64) {
        __syncthreads();
        stage_a_norm<2>(X, row0, kt, WG, BT, srms, As, tid);
#pragma unroll
        for (int i = 0; i < 4; ++i) {
            int cw = i * 256 + w * 64;
            int cid = cw + lane;
            gload16(Bb + (size_t)(cid >> 3) * K + kt + (cid & 7) * 8, Bs + cw * 8);
        }
        __syncthreads();
#pragma unroll
        for (int kk = 0; kk < 64; kk += 32) {
            bf16x8 af[2], bfr[4];
#pragma unroll
            for (int mi = 0; mi < 2; ++mi)
                af[mi] = *(const bf16x8*)(As + (wr * 32 + mi * 16 + lr) * 64 + kk + lg * 8);
#pragma unroll
            for (int ni = 0; ni < 4; ++ni)
                bfr[ni] = *(const bf16x8*)(Bs + (wc * 64 + ni * 16 + lr) * 64 + kk + lg * 8);
#pragma unroll
            for (int mi = 0; mi < 2; ++mi)
#pragma unroll
                for (int ni = 0; ni < 4; ++ni)
                    acc[mi][ni] = MFMA16(af[mi], bfr[ni], acc[mi][ni]);
        }
    }

    if (bn >= 16) {
        // V tile -> VT[b*16+h][d][t]
#pragma unroll
        for (int mi = 0; mi < 2; ++mi) {
#pragma unroll
            for (int ni = 0; ni < 4; ++ni) {
                int r0 = row0 + wr * 32 + mi * 16 + lg * 4;
                int col = bn * 128 + wc * 64 + ni * 16 + lr;
                int h = (col - 2048) >> 6, d = (col - 2048) & 63;
                int bb = r0 >> 10, t0 = r0 & 1023;
                bf16x4 pv;
#pragma unroll
                for (int j = 0; j < 4; ++j) pv[j] = (bf16)acc[mi][ni][j];
                *(bf16x4*)(VTp + (size_t)(bb * 16 + h) * 65536 + (size_t)d * 1024 + t0) = pv;
            }
        }
        return;
    }
#pragma unroll
    for (int mi = 0; mi < 2; ++mi) {
#pragma unroll
        for (int ni = 0; ni < 4; ++ni) {
#pragma unroll
            for (int j = 0; j < 4; ++j) {
                int row = row0 + wr * 32 + mi * 16 + lg * 4 + j;
                int col = bn * 128 + wc * 64 + ni * 16 + lr;
                Cb[(size_t)row * 3072 + col] = (bf16)acc[mi][ni][j];
            }
        }
    }
}

// ---------------- oproj / down: BM=32 (MT=1), residual epilogue + sumsq slices ----------------
// MODE 1: Xout = Xin + acc; write SQout[bn][row]
// MODE 2: Xout = Xin + s*((Xin2-Xin)+acc); write SQout[bn][row]
template <int MODE>
__device__ __forceinline__ void gemm_resid_body(const bf16* __restrict__ A,
                                                const bf16* __restrict__ B,
                                                int GN, int GM, int N, int K,
                                                const float* __restrict__ Xin,
                                                const float* __restrict__ Xin2,
                                                float* __restrict__ Xout,
                                                const float* __restrict__ sptr,
                                                float* __restrict__ SQout) {
    __shared__ __align__(16) bf16 As[32 * 64];
    __shared__ __align__(16) bf16 Bs[128 * 64];
    __shared__ float part[32][2];
    const int wg = xcd_swizzle(blockIdx.x, GN * GM);
    const int bm = wg / GN, bn = wg - bm * GN;   // bn-fastest (A larger)
    const int tid = threadIdx.x, lane = tid & 63, w = tid >> 6;
    const int wr = w >> 1, wc = w & 1, lr = lane & 15, lg = lane >> 4;
    const bf16* Ab = A + (size_t)bm * 32 * K;
    const bf16* Bb = B + (size_t)bn * 128 * K;

    f32x4 acc[4];
#pragma unroll
    for (int j = 0; j < 4; ++j) acc[j] = (f32x4){0.f, 0.f, 0.f, 0.f};

    for (int kt = 0; kt < K; kt += 64) {
        __syncthreads();
        {
            int cid = tid;   // 256 chunks: 32 rows x 8
            int cw = w * 64;
            gload16(Ab + (size_t)(cid >> 3) * K + kt + (cid & 7) * 8, As + cw * 8);
        }
#pragma unroll
        for (int i = 0; i < 4; ++i) {
            int cw = i * 256 + w * 64;
            int cid = cw + lane;
            gload16(Bb + (size_t)(cid >> 3) * K + kt + (cid & 7) * 8, Bs + cw * 8);
        }
        __syncthreads();
#pragma unroll
        for (int kk = 0; kk < 64; kk += 32) {
            bf16x8 af = *(const bf16x8*)(As + (wr * 16 + lr) * 64 + kk + lg * 8);
            bf16x8 bfr[4];
#pragma unroll
            for (int ni = 0; ni < 4; ++ni)
                bfr[ni] = *(const bf16x8*)(Bs + (wc * 64 + ni * 16 + lr) * 64 + kk + lg * 8);
#pragma unroll
            for (int ni = 0; ni < 4; ++ni)
                acc[ni] = MFMA16(af, bfr[ni], acc[ni]);
        }
    }

    float s1 = (MODE == 2) ? sptr[0] : 0.f;
    __syncthreads();   // done with As/Bs reads; part[] writes follow
#pragma unroll
    for (int j = 0; j < 4; ++j) {
        int row = bm * 32 + wr * 16 + lg * 4 + j;
        float sj = 0.f;
#pragma unroll
        for (int ni = 0; ni < 4; ++ni) {
            int col = bn * 128 + wc * 64 + ni * 16 + lr;
            size_t idx = (size_t)row * N + col;
            float v = acc[ni][j];
            float ov;
            if (MODE == 1) ov = Xin[idx] + v;
            else           ov = Xin[idx] + s1 * (Xin2[idx] - Xin[idx] + v);
            Xout[idx] = ov;
            sj += ov * ov;
        }
        sj += __shfl_xor(sj, 1);
        sj += __shfl_xor(sj, 2);
        sj += __shfl_xor(sj, 4);
        sj += __shfl_xor(sj, 8);
        if (lr == 0) part[wr * 16 + lg * 4 + j][wc] = sj;
    }
    __syncthreads();
    if (tid < 32) SQout[bn * 2048 + bm * 32 + tid] = part[tid][0] + part[tid][1];
}

__global__ __launch_bounds__(256, 4) void gemm_oproj(const bf16* A, const bf16* B, int GN, int GM,
                                                     int N, int K, const float* Xin, float* Xout,
                                                     float* SQout) {
    gemm_resid_body<1>(A, B, GN, GM, N, K, Xin, nullptr, Xout, nullptr, SQout);
}
__global__ __launch_bounds__(256, 4) void gemm_down(const bf16* A, const bf16* B, int GN, int GM,
                                                    int N, int K, const float* Xin, const float* Xin2,
                                                    float* Xout, const float* sptr, float* SQout) {
    gemm_resid_body<2>(A, B, GN, GM, N, K, Xin, Xin2, Xout, sptr, SQout);
}

// ---------------- fused gate+up GEMM, norm-fused A, SwiGLU epilogue ----------------
// Tile 64x128 dual-acc; A from f32 X1 + SUMSQ1 slices.
__global__ __launch_bounds__(256, 4) void gemm_gateup(const float* __restrict__ X1,
                                                      const float* __restrict__ SQ1,
                                                      const float* __restrict__ WG,
                                                      const float* __restrict__ BT,
                                                      const bf16* __restrict__ Bg,
                                                      const bf16* __restrict__ Bu,
                                                      bf16* __restrict__ FF) {
    const int K = 1024, N = 2048;
    __shared__ __align__(16) bf16 As[64 * 64];
    __shared__ __align__(16) bf16 Gs[128 * 64];
    __shared__ __align__(16) bf16 Us[128 * 64];
    __shared__ float srms[64];
    const int wg = xcd_swizzle(blockIdx.x, 512);
    const int bn = wg >> 5, bm = wg & 31;      // bm-fastest: B larger
    const int tid = threadIdx.x, lane = tid & 63, w = tid >> 6;
    const int wr = w >> 1, wc = w & 1, lr = lane & 15, lg = lane >> 4;
    const int row0 = bm * 64;
    const bf16* Gb = Bg + (size_t)bn * 128 * K;
    const bf16* Ub = Bu + (size_t)bn * 128 * K;

    if (tid < 64) {
        float s = 0.f;
#pragma unroll
        for (int k = 0; k < 8; ++k) s += SQ1[k * 2048 + row0 + tid];
        srms[tid] = rsqrtf(s * (1.0f / 1024.0f) + RMS_EPS);
    }

    f32x4 ag[2][4], au[2][4];
#pragma unroll
    for (int i = 0; i < 2; ++i)
#pragma unroll
        for (int j = 0; j < 4; ++j) {
            ag[i][j] = (f32x4){0.f, 0.f, 0.f, 0.f};
            au[i][j] = (f32x4){0.f, 0.f, 0.f, 0.f};
        }

    for (int kt = 0; kt < K; kt += 64) {
        __syncthreads();
        stage_a_norm<2>(X1, row0, kt, WG, BT, srms, As, tid);
#pragma unroll
        for (int i = 0; i < 4; ++i) {
            int cw = i * 256 + w * 64;
            int cid = cw + lane;
            size_t ro = (size_t)(cid >> 3) * K + kt + (cid & 7) * 8;
            gload16(Gb + ro, Gs + cw * 8);
            gload16(Ub + ro, Us + cw * 8);
        }
        __syncthreads();
#pragma unroll
        for (int kk = 0; kk < 64; kk += 32) {
            bf16x8 af[2], gf[4], uf[4];
#pragma unroll
            for (int mi = 0; mi < 2; ++mi)
                af[mi] = *(const bf16x8*)(As + (wr * 32 + mi * 16 + lr) * 64 + kk + lg * 8);
#pragma unroll
            for (int ni = 0; ni < 4; ++ni) {
                gf[ni] = *(const bf16x8*)(Gs + (wc * 64 + ni * 16 + lr) * 64 + kk + lg * 8);
                uf[ni] = *(const bf16x8*)(Us + (wc * 64 + ni * 16 + lr) * 64 + kk + lg * 8);
            }
#pragma unroll
            for (int mi = 0; mi < 2; ++mi)
#pragma unroll
                for (int ni = 0; ni < 4; ++ni) {
                    ag[mi][ni] = MFMA16(af[mi], gf[ni], ag[mi][ni]);
                    au[mi][ni] = MFMA16(af[mi], uf[ni], au[mi][ni]);
                }
        }
    }

#pragma unroll
    for (int mi = 0; mi < 2; ++mi) {
#pragma unroll
        for (int ni = 0; ni < 4; ++ni) {
#pragma unroll
            for (int j = 0; j < 4; ++j) {
                int row = row0 + wr * 32 + mi * 16 + lg * 4 + j;
                int col = bn * 128 + wc * 64 + ni * 16 + lr;
                float g = ag[mi][ni][j], u = au[mi][ni][j];
                float sg = g / (1.0f + __expf(-g));
                FF[(size_t)row * N + col] = (bf16)(sg * u);
            }
        }
    }
}

// ---------------- causal flash attention (all-transposed, VT pre-transposed) ----------------

__global__ __launch_bounds__(256) void attn_kernel(const bf16* __restrict__ QKV,
                                                   const bf16* __restrict__ VTg,
                                                   bf16* __restrict__ AO) {
    const int qt = (blockIdx.x & 1) ? (15 - (blockIdx.x >> 1)) : (blockIdx.x >> 1);
    const int bh = blockIdx.y;
    const int b = bh >> 4, h = bh & 15;
    const int tid = threadIdx.x;
    const int w = tid >> 6, lane = tid & 63;
    const int lr = lane & 15, lg = lane >> 4;

    __shared__ __align__(16) bf16 Ks[64 * 72];
    __shared__ __align__(16) bf16 Vt[64 * 72];
    __shared__ __align__(16) bf16 Ps[4 * 16 * 72];
    bf16* Pw = Ps + w * 16 * 72;

    const int qrow = b * 1024 + qt * 64 + w * 16 + lr;
    const bf16* qptr = QKV + (size_t)qrow * 3072 + h * 64;
    const bf16* vt_src = VTg + (size_t)bh * 65536;
    bf16x8 qf0 = *(const bf16x8*)(qptr + lg * 8);
    bf16x8 qf1 = *(const bf16x8*)(qptr + 32 + lg * 8);

    f32x4 o[4];
#pragma unroll
    for (int i = 0; i < 4; ++i) o[i] = (f32x4){0.f, 0.f, 0.f, 0.f};
    float m_run = -1e30f, l_run = 0.f;
    const int gq = qt * 64 + w * 16 + lr;

    for (int kt = 0; kt <= qt; ++kt) {
        __syncthreads();
#pragma unroll
        for (int i = 0; i < 2; ++i) {
            int cid = tid + 256 * i;
            int r = cid >> 3, c8 = (cid & 7) * 8;
            const bf16* kvrow = QKV + (size_t)(b * 1024 + kt * 64 + r) * 3072 + h * 64;
            *(bf16x8*)(Ks + r * 72 + c8) = *(const bf16x8*)(kvrow + 1024 + c8);
            *(bf16x8*)(Vt + r * 72 + c8) =
                *(const bf16x8*)(vt_src + (size_t)r * 1024 + kt * 64 + c8);
        }
        __syncthreads();

        f32x4 st[4];
#pragma unroll
        for (int i = 0; i < 4; ++i) st[i] = (f32x4){0.f, 0.f, 0.f, 0.f};
        __builtin_amdgcn_s_setprio(1);
#pragma unroll
        for (int ki = 0; ki < 4; ++ki) {
            bf16x8 kf0 = *(const bf16x8*)(Ks + (ki * 16 + lr) * 72 + lg * 8);
            bf16x8 kf1 = *(const bf16x8*)(Ks + (ki * 16 + lr) * 72 + 32 + lg * 8);
            st[ki] = MFMA16(kf0, qf0, st[ki]);
            st[ki] = MFMA16(kf1, qf1, st[ki]);
        }
        __builtin_amdgcn_s_setprio(0);
        bool diag = (kt == qt);
        float pm = -1e30f;
#pragma unroll
        for (int ki = 0; ki < 4; ++ki) {
#pragma unroll
            for (int j = 0; j < 4; ++j) {
                float sv = st[ki][j] * 0.125f;
                if (diag) {
                    int gk = kt * 64 + ki * 16 + lg * 4 + j;
                    if (gk > gq) sv = -1e30f;
                }
                st[ki][j] = sv;
                pm = fmaxf(pm, sv);
            }
        }
        pm = fmaxf(pm, __shfl_xor(pm, 16));
        pm = fmaxf(pm, __shfl_xor(pm, 32));
        float m_new = fmaxf(m_run, pm);
        float alpha = __expf(m_run - m_new);
        float rs = 0.f;
#pragma unroll
        for (int ki = 0; ki < 4; ++ki) {
            bf16x4 pb;
#pragma unroll
            for (int j = 0; j < 4; ++j) {
                float pv = __expf(st[ki][j] - m_new);
                rs += pv;
                pb[j] = (bf16)pv;
            }
            *(bf16x4*)(Pw + lr * 72 + ki * 16 + lg * 4) = pb;
        }
        rs += __shfl_xor(rs, 16);
        rs += __shfl_xor(rs, 32);
        l_run = l_run * alpha + rs;
        m_run = m_new;
#pragma unroll
        for (int di = 0; di < 4; ++di) o[di] *= alpha;
        __builtin_amdgcn_s_setprio(1);
#pragma unroll
        for (int dk = 0; dk < 2; ++dk) {
            bf16x8 pf = *(const bf16x8*)(Pw + lr * 72 + dk * 32 + lg * 8);
#pragma unroll
            for (int di = 0; di < 4; ++di) {
                bf16x8 vf = *(const bf16x8*)(Vt + (di * 16 + lr) * 72 + dk * 32 + lg * 8);
                o[di] = MFMA16(vf, pf, o[di]);
            }
        }
        __builtin_amdgcn_s_setprio(0);
    }
    float inv = 1.0f / l_run;
    bf16* optr = AO + (size_t)qrow * 1024 + h * 64;
#pragma unroll
    for (int di = 0; di < 4; ++di) {
        bf16x4 ov;
#pragma unroll
        for (int j = 0; j < 4; ++j) ov[j] = (bf16)(o[di][j] * inv);
        *(bf16x4*)(optr + di * 16 + lg * 4) = ov;
    }
}

// ---------------- driver ----------------

extern "C" void kernel_launch(void* const* d_in, const int* in_sizes, int n_in,
                              void* d_out, int out_size, void* d_ws, size_t ws_size,
                              hipStream_t stream) {
    const int* tokens = (const int*)d_in[0];
    const float* embed_w = (const float*)d_in[1];
    const float* qkv_w = (const float*)d_in[2];
    const float* o_w = (const float*)d_in[3];
    const float* gate_w = (const float*)d_in[4];
    const float* up_w = (const float*)d_in[5];
    const float* down_w = (const float*)d_in[6];
    const float* norm1_w = (const float*)d_in[7];
    const float* norm2_w = (const float*)d_in[8];
    const float* scale_gamma = (const float*)d_in[9];
    const float* scale_beta = (const float*)d_in[10];
    const float* iter_scale = (const float*)d_in[11];
    const float* norm_w = (const float*)d_in[12];
    const float* lm_head_w = (const float*)d_in[13];

    char* p = (char*)d_ws;
    auto alloc = [&](size_t nbytes) -> char* {
        char* r = p;
        p += (nbytes + 255) & ~(size_t)255;
        return r;
    };
    bf16* WQKV = (bf16*)alloc(3072ull * 1024 * 2);
    bf16* WO   = (bf16*)alloc(1024ull * 1024 * 2);
    bf16* WG   = (bf16*)alloc(2048ull * 1024 * 2);
    bf16* WU   = (bf16*)alloc(2048ull * 1024 * 2);
    bf16* WD   = (bf16*)alloc(1024ull * 2048 * 2);
    bf16* WLM  = (bf16*)alloc(32000ull * 1024 * 2);
    float* X   = (float*)alloc(2048ull * 1024 * 4);
    float* X1  = (float*)alloc(2048ull * 1024 * 4);
    bf16* H    = (bf16*)alloc(2048ull * 1024 * 2);
    bf16* QKVb = (bf16*)alloc(2048ull * 3072 * 2);
    bf16* VT   = (bf16*)alloc(2048ull * 1024 * 2);
    bf16* AO   = (bf16*)alloc(2048ull * 1024 * 2);
    bf16* FF   = (bf16*)alloc(2048ull * 2048 * 2);
    float* SQ0 = (float*)alloc(8ull * 2048 * 4);
    float* SQ1 = (float*)alloc(8ull * 2048 * 4);
    float* WG1 = (float*)alloc(4ull * 1024 * 4);
    float* WG2 = (float*)alloc(4ull * 1024 * 4);

    cvt_kernel<<<1024, 256, 0, stream>>>(qkv_w, WQKV, 3072 * 1024 / 4);
    cvt_kernel<<<1024, 256, 0, stream>>>(o_w, WO, 1024 * 1024 / 4);
    cvt_kernel<<<1024, 256, 0, stream>>>(gate_w, WG, 2048 * 1024 / 4);
    cvt_kernel<<<1024, 256, 0, stream>>>(up_w, WU, 2048 * 1024 / 4);
    cvt_kernel<<<1024, 256, 0, stream>>>(down_w, WD, 1024 * 2048 / 4);
    cvt_kernel<<<2048, 256, 0, stream>>>(lm_head_w, WLM, 32000 * 1024 / 4);
    wg_kernel<<<8, 256, 0, stream>>>(norm1_w, norm2_w, scale_gamma, WG1, WG2);
    embed_kernel<<<2048, 256, 0, stream>>>(tokens, embed_w, X, SQ0);

    for (int l = 0; l < 32; ++l) {
        int s = l >> 3;
        const float* bt = scale_beta + (size_t)s * 1024;
        // QKV: norm1 fused from X/SQ0; V-transpose epilogue
        gemm_qkv<<<24 * 32, 256, 0, stream>>>(X, SQ0, WG1 + s * 1024, bt, WQKV, QKVb, VT);
        attn_kernel<<<dim3(16, 32), 256, 0, stream>>>(QKVb, VT, AO);
        // o-proj: residual + SQ1 slices
        gemm_oproj<<<8 * 64, 256, 0, stream>>>(AO, WO, 8, 64, 1024, 1024, X, X1, SQ1);
        // gate+up: norm2 fused from X1/SQ1
        gemm_gateup<<<512, 256, 0, stream>>>(X1, SQ1, WG2 + s * 1024, bt, WG, WU, FF);
        // down: fractal update + SQ0 slices for next layer
        gemm_down<<<8 * 64, 256, 0, stream>>>(FF, WD, 8, 64, 1024, 2048, X, X1, X,
                                              iter_scale + l, SQ0);
    }
    rmsnorm_kernel<<<2048, 256, 0, stream>>>(X, norm_w, H);
    gemm_lmhead<<<250 * 16, 256, 0, stream>>>(H, WLM, 250, 16, 32000, 1024, (float*)d_out);
}

// Round 13
// 4590.364 us; speedup vs baseline: 1.1177x; 1.1177x over previous
//
#include <hip/hip_runtime.h>

typedef __bf16 bf16;
typedef __attribute__((ext_vector_type(8))) __bf16 bf16x8;
typedef __attribute__((ext_vector_type(4))) __bf16 bf16x4;
typedef __attribute__((ext_vector_type(4))) float f32x4;

#define MFMA16(a,b,c) __builtin_amdgcn_mfma_f32_16x16x32_bf16((a),(b),(c),0,0,0)

__device__ __forceinline__ void gload16(const void* g, void* l) {
    __builtin_amdgcn_global_load_lds((const __attribute__((address_space(1))) void*)g,
                                     (__attribute__((address_space(3))) void*)l, 16, 0, 0);
}

// bijective XCD-chunked block swizzle (m204)
__device__ __forceinline__ int xcd_swizzle(int orig, int nwg) {
    int q = nwg >> 3, r = nwg & 7;
    int xcd = orig & 7, loc = orig >> 3;
    int base = (xcd < r) ? xcd * (q + 1) : r * (q + 1) + (xcd - r) * q;
    return base + loc;
}

// ---------------- elementwise / small kernels ----------------

// batched f32->bf16 weight convert: 6 segments, compile-time bounds (float4 units)
__global__ __launch_bounds__(256) void cvt6_kernel(const float* __restrict__ s0,  // qkv   786432
                                                   const float* __restrict__ s1,  // o     262144
                                                   const float* __restrict__ s2,  // gate  524288
                                                   const float* __restrict__ s3,  // up    524288
                                                   const float* __restrict__ s4,  // down  524288
                                                   const float* __restrict__ s5,  // lm    8192000
                                                   bf16* __restrict__ d0, bf16* __restrict__ d1,
                                                   bf16* __restrict__ d2, bf16* __restrict__ d3,
                                                   bf16* __restrict__ d4, bf16* __restrict__ d5) {
    const int E0 = 786432, E1 = 1048576, E2 = 1572864, E3 = 2097152, E4 = 2621440, E5 = 10813440;
    int stride = gridDim.x * 256;
    for (int i = blockIdx.x * 256 + threadIdx.x; i < E5; i += stride) {
        const float* src; bf16* dst; int li;
        if (i < E0)      { src = s0; dst = d0; li = i; }
        else if (i < E1) { src = s1; dst = d1; li = i - E0; }
        else if (i < E2) { src = s2; dst = d2; li = i - E1; }
        else if (i < E3) { src = s3; dst = d3; li = i - E2; }
        else if (i < E4) { src = s4; dst = d4; li = i - E3; }
        else             { src = s5; dst = d5; li = i - E4; }
        float4 v = ((const float4*)src)[li];
        bf16x4 o;
        o[0] = (bf16)v.x; o[1] = (bf16)v.y; o[2] = (bf16)v.z; o[3] = (bf16)v.w;
        ((bf16x4*)dst)[li] = o;
    }
}

__global__ __launch_bounds__(256) void embed_kernel(const int* __restrict__ tok,
                                                    const float* __restrict__ ew,
                                                    float* __restrict__ X) {
    int m = blockIdx.x;
    int t = tok[m];
    ((float4*)(X + (size_t)m * 1024))[threadIdx.x] =
        ((const float4*)(ew + (size_t)t * 1024))[threadIdx.x];
}

template <bool FILM>
__global__ __launch_bounds__(256) void rmsnorm_kernel(const float* __restrict__ X,
                                                      const float* __restrict__ w,
                                                      const float* __restrict__ gamma,
                                                      const float* __restrict__ beta,
                                                      bf16* __restrict__ H) {
    int m = blockIdx.x, t = threadIdx.x;
    float4 xv = ((const float4*)(X + (size_t)m * 1024))[t];
    float ss = xv.x * xv.x + xv.y * xv.y + xv.z * xv.z + xv.w * xv.w;
#pragma unroll
    for (int off = 1; off < 64; off <<= 1) ss += __shfl_xor(ss, off);
    __shared__ float red[4];
    if ((t & 63) == 0) red[t >> 6] = ss;
    __syncthreads();
    float tot = red[0] + red[1] + red[2] + red[3];
    float sc = rsqrtf(tot * (1.0f / 1024.0f) + 1.1920929e-07f);
    float4 wv = ((const float4*)w)[t];
    float r0 = xv.x * sc * wv.x, r1 = xv.y * sc * wv.y;
    float r2 = xv.z * sc * wv.z, r3 = xv.w * sc * wv.w;
    if (FILM) {
        float4 gv = ((const float4*)gamma)[t];
        float4 bv = ((const float4*)beta)[t];
        r0 = r0 * gv.x + bv.x; r1 = r1 * gv.y + bv.y;
        r2 = r2 * gv.z + bv.z; r3 = r3 * gv.w + bv.w;
    }
    bf16x4 o;
    o[0] = (bf16)r0; o[1] = (bf16)r1; o[2] = (bf16)r2; o[3] = (bf16)r3;
    ((bf16x4*)(H + (size_t)m * 1024))[t] = o;
}

// ---------------- GEMM body: C[M,N] = A[M,K] @ B[N,K]^T, gload_lds staging ----------------
// MT: row-fragments/wave (BM = 32*MT). Single-buffer round-5 structure.
// MODE 0: Cb = bf16(acc)
// MODE 1: Xout = Xin + acc                       (o-proj residual)
// MODE 2: Xout = Xin + s*((Xin2-Xin) + acc)      (fractal update)
// MODE 3: Cf = acc                               (lm_head, f32 out)
// MODE 4: QKV fused: bn<16 -> Cb (Q|K slices); bn>=16 -> VT[bh][d][t] (V transposed)

template <int MT, int MODE, bool BNF>
__device__ __forceinline__ void gemm_body(const bf16* __restrict__ A,
                                          const bf16* __restrict__ B,
                                          int GN, int GM, int N, int K,
                                          bf16* __restrict__ Cb, float* __restrict__ Cf,
                                          const float* __restrict__ Xin,
                                          const float* __restrict__ Xin2,
                                          float* __restrict__ Xout,
                                          const float* __restrict__ sptr,
                                          bf16* __restrict__ VTp) {
    constexpr int BM = 32 * MT;
    __shared__ __align__(16) bf16 As[BM * 64];
    __shared__ __align__(16) bf16 Bs[128 * 64];
    const int wg = xcd_swizzle(blockIdx.x, GN * GM);
    int bn, bm;
    if (BNF) { bm = wg / GN; bn = wg - bm * GN; }
    else     { bn = wg / GM; bm = wg - bn * GM; }
    const int tid = threadIdx.x, lane = tid & 63, w = tid >> 6;
    const int wr = w >> 1, wc = w & 1, lr = lane & 15, lg = lane >> 4;
    const bf16* Ab = A + (size_t)bm * BM * K;
    const bf16* Bb = B + (size_t)bn * 128 * K;

    f32x4 acc[MT][4];
#pragma unroll
    for (int i = 0; i < MT; ++i)
#pragma unroll
        for (int j = 0; j < 4; ++j) acc[i][j] = (f32x4){0.f, 0.f, 0.f, 0.f};

    for (int kt = 0; kt < K; kt += 64) {
        __syncthreads();
#pragma unroll
        for (int i = 0; i < MT; ++i) {
            int cw = i * 256 + w * 64;
            int cid = cw + lane;
            gload16(Ab + (size_t)(cid >> 3) * K + kt + (cid & 7) * 8, As + cw * 8);
        }
#pragma unroll
        for (int i = 0; i < 4; ++i) {
            int cw = i * 256 + w * 64;
            int cid = cw + lane;
            gload16(Bb + (size_t)(cid >> 3) * K + kt + (cid & 7) * 8, Bs + cw * 8);
        }
        __syncthreads();
#pragma unroll
        for (int kk = 0; kk < 64; kk += 32) {
            bf16x8 af[MT], bfr[4];
#pragma unroll
            for (int mi = 0; mi < MT; ++mi)
                af[mi] = *(const bf16x8*)(As + (wr * (16 * MT) + mi * 16 + lr) * 64 + kk + lg * 8);
#pragma unroll
            for (int ni = 0; ni < 4; ++ni)
                bfr[ni] = *(const bf16x8*)(Bs + (wc * 64 + ni * 16 + lr) * 64 + kk + lg * 8);
#pragma unroll
            for (int mi = 0; mi < MT; ++mi)
#pragma unroll
                for (int ni = 0; ni < 4; ++ni)
                    acc[mi][ni] = MFMA16(af[mi], bfr[ni], acc[mi][ni]);
        }
    }

    float s1 = (MODE == 2) ? sptr[0] : 0.f;
    if (MODE == 4 && bn >= 16) {
        // V tile: write transposed VT[b*16+h][d][t], t fast. Block-uniform branch.
#pragma unroll
        for (int mi = 0; mi < MT; ++mi) {
#pragma unroll
            for (int ni = 0; ni < 4; ++ni) {
                int row0 = bm * BM + wr * (16 * MT) + mi * 16 + lg * 4;   // t..t+3
                int col = bn * 128 + wc * 64 + ni * 16 + lr;              // 2048 + h*64 + d
                int h = (col - 2048) >> 6, d = (col - 2048) & 63;
                int bb = row0 >> 10, t0 = row0 & 1023;
                bf16x4 pv;
#pragma unroll
                for (int j = 0; j < 4; ++j) pv[j] = (bf16)acc[mi][ni][j];
                *(bf16x4*)(VTp + (size_t)(bb * 16 + h) * 65536 + (size_t)d * 1024 + t0) = pv;
            }
        }
        return;
    }
#pragma unroll
    for (int mi = 0; mi < MT; ++mi) {
#pragma unroll
        for (int ni = 0; ni < 4; ++ni) {
#pragma unroll
            for (int j = 0; j < 4; ++j) {
                int row = bm * BM + wr * (16 * MT) + mi * 16 + lg * 4 + j;
                int col = bn * 128 + wc * 64 + ni * 16 + lr;
                size_t idx = (size_t)row * N + col;
                float v = acc[mi][ni][j];
                if (MODE == 0 || MODE == 4) Cb[idx] = (bf16)v;
                else if (MODE == 1) Xout[idx] = Xin[idx] + v;
                else if (MODE == 2) Xout[idx] = Xin[idx] + s1 * (Xin2[idx] - Xin[idx] + v);
                else Cf[idx] = v;
            }
        }
    }
}

// Uniquely-named wrappers per call-site (profiler attribution + per-site tiling).
__global__ __launch_bounds__(256, 4) void gemm_qkv(const bf16* A, const bf16* B, int GN, int GM,
                                                   int N, int K, bf16* Cb, bf16* VTp) {
    gemm_body<2, 4, false>(A, B, GN, GM, N, K, Cb, nullptr, nullptr, nullptr, nullptr, nullptr, VTp);
}
// oproj/down: BM=32 (MT=1) -> 512 blocks = 2 waves/SIMD.
__global__ __launch_bounds__(256, 4) void gemm_oproj(const bf16* A, const bf16* B, int GN, int GM,
                                                     int N, int K, const float* Xin, float* Xout) {
    gemm_body<1, 1, true>(A, B, GN, GM, N, K, nullptr, nullptr, Xin, nullptr, Xout, nullptr, nullptr);
}
__global__ __launch_bounds__(256, 4) void gemm_down(const bf16* A, const bf16* B, int GN, int GM,
                                                    int N, int K, const float* Xin, const float* Xin2,
                                                    float* Xout, const float* sptr) {
    gemm_body<1, 2, true>(A, B, GN, GM, N, K, nullptr, nullptr, Xin, Xin2, Xout, sptr, nullptr);
}
// lm_head: MT=4 (arithmetic intensity) + 128-reg cap (4 blocks/CU occupancy).
__global__ __launch_bounds__(256, 4) void gemm_lmhead(const bf16* A, const bf16* B, int GN, int GM,
                                                      int N, int K, float* Cf) {
    gemm_body<4, 3, false>(A, B, GN, GM, N, K, nullptr, Cf, nullptr, nullptr, nullptr, nullptr, nullptr);
}

// ---------------- fused gate+up GEMM with SwiGLU epilogue ----------------
// Tile 64x128 dual-acc (64 AGPR + ~50 VGPR -> 16 waves/CU; LDS 40KB).

__global__ __launch_bounds__(256, 4) void gemm_gateup(const bf16* __restrict__ A,
                                                      const bf16* __restrict__ Bg,
                                                      const bf16* __restrict__ Bu,
                                                      bf16* __restrict__ FF) {
    const int K = 1024, N = 2048;
    __shared__ __align__(16) bf16 As[64 * 64];
    __shared__ __align__(16) bf16 Gs[128 * 64];
    __shared__ __align__(16) bf16 Us[128 * 64];
    const int wg = xcd_swizzle(blockIdx.x, 512);
    const int bn = wg >> 5, bm = wg & 31;      // bm-fastest: B (8MB) larger than A (4MB)
    const int tid = threadIdx.x, lane = tid & 63, w = tid >> 6;
    const int wr = w >> 1, wc = w & 1, lr = lane & 15, lg = lane >> 4;
    const bf16* Ab = A + (size_t)bm * 64 * K;
    const bf16* Gb = Bg + (size_t)bn * 128 * K;
    const bf16* Ub = Bu + (size_t)bn * 128 * K;

    f32x4 ag[2][4], au[2][4];
#pragma unroll
    for (int i = 0; i < 2; ++i)
#pragma unroll
        for (int j = 0; j < 4; ++j) {
            ag[i][j] = (f32x4){0.f, 0.f, 0.f, 0.f};
            au[i][j] = (f32x4){0.f, 0.f, 0.f, 0.f};
        }

    for (int kt = 0; kt < K; kt += 64) {
        __syncthreads();
#pragma unroll
        for (int i = 0; i < 2; ++i) {
            int cw = i * 256 + w * 64;
            int cid = cw + lane;
            gload16(Ab + (size_t)(cid >> 3) * K + kt + (cid & 7) * 8, As + cw * 8);
        }
#pragma unroll
        for (int i = 0; i < 4; ++i) {
            int cw = i * 256 + w * 64;
            int cid = cw + lane;
            size_t ro = (size_t)(cid >> 3) * K + kt + (cid & 7) * 8;
            gload16(Gb + ro, Gs + cw * 8);
            gload16(Ub + ro, Us + cw * 8);
        }
        __syncthreads();
#pragma unroll
        for (int kk = 0; kk < 64; kk += 32) {
            bf16x8 af[2], gf[4], uf[4];
#pragma unroll
            for (int mi = 0; mi < 2; ++mi)
                af[mi] = *(const bf16x8*)(As + (wr * 32 + mi * 16 + lr) * 64 + kk + lg * 8);
#pragma unroll
            for (int ni = 0; ni < 4; ++ni) {
                gf[ni] = *(const bf16x8*)(Gs + (wc * 64 + ni * 16 + lr) * 64 + kk + lg * 8);
                uf[ni] = *(const bf16x8*)(Us + (wc * 64 + ni * 16 + lr) * 64 + kk + lg * 8);
            }
#pragma unroll
            for (int mi = 0; mi < 2; ++mi)
#pragma unroll
                for (int ni = 0; ni < 4; ++ni) {
                    ag[mi][ni] = MFMA16(af[mi], gf[ni], ag[mi][ni]);
                    au[mi][ni] = MFMA16(af[mi], uf[ni], au[mi][ni]);
                }
        }
    }

#pragma unroll
    for (int mi = 0; mi < 2; ++mi) {
#pragma unroll
        for (int ni = 0; ni < 4; ++ni) {
#pragma unroll
            for (int j = 0; j < 4; ++j) {
                int row = bm * 64 + wr * 32 + mi * 16 + lg * 4 + j;
                int col = bn * 128 + wc * 64 + ni * 16 + lr;
                float g = ag[mi][ni][j], u = au[mi][ni][j];
                float sg = g / (1.0f + __expf(-g));
                FF[(size_t)row * N + col] = (bf16)(sg * u);
            }
        }
    }
}

// ---------------- causal flash attention (all-transposed form, VT pre-transposed) ----------------
// qt pair-swizzle: consecutive blocks get (q, 15-q) so per-CU work is balanced.

__global__ __launch_bounds__(256) void attn_kernel(const bf16* __restrict__ QKV,
                                                   const bf16* __restrict__ VTg,
                                                   bf16* __restrict__ AO) {
    const int qt = (blockIdx.x & 1) ? (15 - (blockIdx.x >> 1)) : (blockIdx.x >> 1);
    const int bh = blockIdx.y;
    const int b = bh >> 4, h = bh & 15;
    const int tid = threadIdx.x;
    const int w = tid >> 6, lane = tid & 63;
    const int lr = lane & 15, lg = lane >> 4;

    __shared__ __align__(16) bf16 Ks[64 * 72];
    __shared__ __align__(16) bf16 Vt[64 * 72];
    __shared__ __align__(16) bf16 Ps[4 * 16 * 72];
    bf16* Pw = Ps + w * 16 * 72;

    const int qrow = b * 1024 + qt * 64 + w * 16 + lr;
    const bf16* qptr = QKV + (size_t)qrow * 3072 + h * 64;
    const bf16* vt_src = VTg + (size_t)bh * 65536;
    bf16x8 qf0 = *(const bf16x8*)(qptr + lg * 8);
    bf16x8 qf1 = *(const bf16x8*)(qptr + 32 + lg * 8);

    f32x4 o[4];
#pragma unroll
    for (int i = 0; i < 4; ++i) o[i] = (f32x4){0.f, 0.f, 0.f, 0.f};
    float m_run = -1e30f, l_run = 0.f;
    const int gq = qt * 64 + w * 16 + lr;

    for (int kt = 0; kt <= qt; ++kt) {
        __syncthreads();
#pragma unroll
        for (int i = 0; i < 2; ++i) {
            int cid = tid + 256 * i;
            int r = cid >> 3, c8 = (cid & 7) * 8;
            const bf16* kvrow = QKV + (size_t)(b * 1024 + kt * 64 + r) * 3072 + h * 64;
            *(bf16x8*)(Ks + r * 72 + c8) = *(const bf16x8*)(kvrow + 1024 + c8);
            *(bf16x8*)(Vt + r * 72 + c8) =
                *(const bf16x8*)(vt_src + (size_t)r * 1024 + kt * 64 + c8);
        }
        __syncthreads();

        f32x4 st[4];
#pragma unroll
        for (int i = 0; i < 4; ++i) st[i] = (f32x4){0.f, 0.f, 0.f, 0.f};
        __builtin_amdgcn_s_setprio(1);
#pragma unroll
        for (int ki = 0; ki < 4; ++ki) {
            bf16x8 kf0 = *(const bf16x8*)(Ks + (ki * 16 + lr) * 72 + lg * 8);
            bf16x8 kf1 = *(const bf16x8*)(Ks + (ki * 16 + lr) * 72 + 32 + lg * 8);
            st[ki] = MFMA16(kf0, qf0, st[ki]);
            st[ki] = MFMA16(kf1, qf1, st[ki]);
        }
        __builtin_amdgcn_s_setprio(0);
        bool diag = (kt == qt);
        float pm = -1e30f;
#pragma unroll
        for (int ki = 0; ki < 4; ++ki) {
#pragma unroll
            for (int j = 0; j < 4; ++j) {
                float sv = st[ki][j] * 0.125f;
                if (diag) {
                    int gk = kt * 64 + ki * 16 + lg * 4 + j;
                    if (gk > gq) sv = -1e30f;
                }
                st[ki][j] = sv;
                pm = fmaxf(pm, sv);
            }
        }
        pm = fmaxf(pm, __shfl_xor(pm, 16));
        pm = fmaxf(pm, __shfl_xor(pm, 32));
        float m_new = fmaxf(m_run, pm);
        float alpha = __expf(m_run - m_new);
        float rs = 0.f;
#pragma unroll
        for (int ki = 0; ki < 4; ++ki) {
            bf16x4 pb;
#pragma unroll
            for (int j = 0; j < 4; ++j) {
                float pv = __expf(st[ki][j] - m_new);
                rs += pv;
                pb[j] = (bf16)pv;
            }
            *(bf16x4*)(Pw + lr * 72 + ki * 16 + lg * 4) = pb;
        }
        rs += __shfl_xor(rs, 16);
        rs += __shfl_xor(rs, 32);
        l_run = l_run * alpha + rs;
        m_run = m_new;
#pragma unroll
        for (int di = 0; di < 4; ++di) o[di] *= alpha;
        __builtin_amdgcn_s_setprio(1);
#pragma unroll
        for (int dk = 0; dk < 2; ++dk) {
            bf16x8 pf = *(const bf16x8*)(Pw + lr * 72 + dk * 32 + lg * 8);
#pragma unroll
            for (int di = 0; di < 4; ++di) {
                bf16x8 vf = *(const bf16x8*)(Vt + (di * 16 + lr) * 72 + dk * 32 + lg * 8);
                o[di] = MFMA16(vf, pf, o[di]);
            }
        }
        __builtin_amdgcn_s_setprio(0);
    }
    float inv = 1.0f / l_run;
    bf16* optr = AO + (size_t)qrow * 1024 + h * 64;
#pragma unroll
    for (int di = 0; di < 4; ++di) {
        bf16x4 ov;
#pragma unroll
        for (int j = 0; j < 4; ++j) ov[j] = (bf16)(o[di][j] * inv);
        *(bf16x4*)(optr + di * 16 + lg * 4) = ov;
    }
}

// ---------------- driver ----------------

extern "C" void kernel_launch(void* const* d_in, const int* in_sizes, int n_in,
                              void* d_out, int out_size, void* d_ws, size_t ws_size,
                              hipStream_t stream) {
    const int* tokens = (const int*)d_in[0];
    const float* embed_w = (const float*)d_in[1];
    const float* qkv_w = (const float*)d_in[2];
    const float* o_w = (const float*)d_in[3];
    const float* gate_w = (const float*)d_in[4];
    const float* up_w = (const float*)d_in[5];
    const float* down_w = (const float*)d_in[6];
    const float* norm1_w = (const float*)d_in[7];
    const float* norm2_w = (const float*)d_in[8];
    const float* scale_gamma = (const float*)d_in[9];
    const float* scale_beta = (const float*)d_in[10];
    const float* iter_scale = (const float*)d_in[11];
    const float* norm_w = (const float*)d_in[12];
    const float* lm_head_w = (const float*)d_in[13];

    char* p = (char*)d_ws;
    auto alloc = [&](size_t nbytes) -> char* {
        char* r = p;
        p += (nbytes + 255) & ~(size_t)255;
        return r;
    };
    bf16* WQKV = (bf16*)alloc(3072ull * 1024 * 2);
    bf16* WO   = (bf16*)alloc(1024ull * 1024 * 2);
    bf16* WG   = (bf16*)alloc(2048ull * 1024 * 2);
    bf16* WU   = (bf16*)alloc(2048ull * 1024 * 2);
    bf16* WD   = (bf16*)alloc(1024ull * 2048 * 2);
    bf16* WLM  = (bf16*)alloc(32000ull * 1024 * 2);
    float* X   = (float*)alloc(2048ull * 1024 * 4);
    float* X1  = (float*)alloc(2048ull * 1024 * 4);
    bf16* H    = (bf16*)alloc(2048ull * 1024 * 2);
    bf16* QKVb = (bf16*)alloc(2048ull * 3072 * 2);
    bf16* VT   = (bf16*)alloc(2048ull * 1024 * 2);
    bf16* AO   = (bf16*)alloc(2048ull * 1024 * 2);
    bf16* FF   = (bf16*)alloc(2048ull * 2048 * 2);

    cvt6_kernel<<<2048, 256, 0, stream>>>(qkv_w, o_w, gate_w, up_w, down_w, lm_head_w,
                                          WQKV, WO, WG, WU, WD, WLM);
    embed_kernel<<<2048, 256, 0, stream>>>(tokens, embed_w, X);

    for (int l = 0; l < 32; ++l) {
        const float* gm = scale_gamma + (size_t)(l >> 3) * 1024;
        const float* bt = scale_beta + (size_t)(l >> 3) * 1024;
        rmsnorm_kernel<true><<<2048, 256, 0, stream>>>(X, norm1_w, gm, bt, H);
        // QKV fused with V-transpose epilogue: B=6MB > A=4MB -> bm-fastest
        gemm_qkv<<<24 * 32, 256, 0, stream>>>(H, WQKV, 24, 32, 3072, 1024, QKVb, VT);
        attn_kernel<<<dim3(16, 32), 256, 0, stream>>>(QKVb, VT, AO);
        // o-proj: A=4MB > B=2MB -> bn-fastest; BM=32 -> 512 blocks
        gemm_oproj<<<8 * 64, 256, 0, stream>>>(AO, WO, 8, 64, 1024, 1024, X, X1);
        rmsnorm_kernel<true><<<2048, 256, 0, stream>>>(X1, norm2_w, gm, bt, H);
        gemm_gateup<<<512, 256, 0, stream>>>(H, WG, WU, FF);
        // down: A=8MB > B=4MB -> bn-fastest; BM=32 -> 512 blocks
        gemm_down<<<8 * 64, 256, 0, stream>>>(FF, WD, 8, 64, 1024, 2048, X, X1, X, iter_scale + l);
    }
    rmsnorm_kernel<false><<<2048, 256, 0, stream>>>(X, norm_w, nullptr, nullptr, H);
    // lm_head: B=65MB >> A=4MB -> bm-fastest; MT=4 + 128-reg cap (4 blocks/CU)
    gemm_lmhead<<<250 * 16, 256, 0, stream>>>(H, WLM, 250, 16, 32000, 1024, (float*)d_out);
}